// Round 1
// baseline (73.859 us; speedup 1.0000x reference)
//
#include <hip/hip_runtime.h>

#define N_TOK 8192
#define EMB 1024
#define KNOISE 10
#define NORM_TERM 9.0f

__global__ __launch_bounds__(256) void nce_token_kernel(
    const float* __restrict__ input,
    const float* __restrict__ weight,
    const float* __restrict__ bias,
    const float* __restrict__ noise,
    const int* __restrict__ target,
    const int* __restrict__ noise_samples,
    float* __restrict__ token_loss)
{
    __shared__ float4 s_in[EMB / 4];   // 1024 floats = 4 KB
    __shared__ float s_dot[16];        // 11 used

    const int n = blockIdx.x;
    const int tid = threadIdx.x;
    const int wave = tid >> 6;
    const int lane = tid & 63;

    // Stage input row in LDS: 256 float4 loads, one per thread (coalesced).
    s_in[tid] = reinterpret_cast<const float4*>(input + (size_t)n * EMB)[tid];
    __syncthreads();

    // 11 dot products; wave w handles k = w, w+4, w+8.
    for (int k = wave; k < KNOISE + 1; k += 4) {
        const int row = (k == 0) ? target[n] : noise_samples[n * KNOISE + (k - 1)];
        const float4* wrow = reinterpret_cast<const float4*>(weight + (size_t)row * EMB);
        float acc = 0.f;
        #pragma unroll
        for (int j = 0; j < 4; ++j) {
            const float4 w4 = wrow[lane + 64 * j];   // coalesced 16B/lane
            const float4 i4 = s_in[lane + 64 * j];
            acc = fmaf(w4.x, i4.x, acc);
            acc = fmaf(w4.y, i4.y, acc);
            acc = fmaf(w4.z, i4.z, acc);
            acc = fmaf(w4.w, i4.w, acc);
        }
        // 64-lane butterfly reduce
        #pragma unroll
        for (int off = 32; off > 0; off >>= 1)
            acc += __shfl_xor(acc, off, 64);
        if (lane == 0) s_dot[k] = acc + bias[row];
    }
    __syncthreads();

    if (tid == 0) {
        const int t = target[n];
        const float p0 = expf(s_dot[0] - NORM_TERM);
        const float kn0 = (float)KNOISE * noise[t];
        float loss = logf(p0 / (p0 + kn0));
        #pragma unroll
        for (int k = 0; k < KNOISE; ++k) {
            const int s = noise_samples[n * KNOISE + k];
            const float pk = expf(s_dot[k + 1] - NORM_TERM);
            const float kn = (float)KNOISE * noise[s];
            loss += logf(kn / (pk + kn));
        }
        token_loss[n] = loss;
    }
}

__global__ __launch_bounds__(256) void nce_reduce_kernel(
    const float* __restrict__ token_loss, float* __restrict__ out)
{
    __shared__ float s_part[4];
    float acc = 0.f;
    for (int i = threadIdx.x; i < N_TOK; i += 256)
        acc += token_loss[i];
    #pragma unroll
    for (int off = 32; off > 0; off >>= 1)
        acc += __shfl_xor(acc, off, 64);
    const int wave = threadIdx.x >> 6;
    const int lane = threadIdx.x & 63;
    if (lane == 0) s_part[wave] = acc;
    __syncthreads();
    if (threadIdx.x == 0) {
        const float total = s_part[0] + s_part[1] + s_part[2] + s_part[3];
        out[0] = -total / (float)N_TOK;
    }
}

extern "C" void kernel_launch(void* const* d_in, const int* in_sizes, int n_in,
                              void* d_out, int out_size, void* d_ws, size_t ws_size,
                              hipStream_t stream) {
    const float* input         = (const float*)d_in[0];
    const float* weight        = (const float*)d_in[1];
    const float* bias          = (const float*)d_in[2];
    const float* noise         = (const float*)d_in[3];
    const int*   target        = (const int*)d_in[4];
    const int*   noise_samples = (const int*)d_in[5];

    float* token_loss = (float*)d_ws;   // 8192 floats = 32 KB scratch

    nce_token_kernel<<<N_TOK, 256, 0, stream>>>(
        input, weight, bias, noise, target, noise_samples, token_loss);
    nce_reduce_kernel<<<1, 256, 0, stream>>>(token_loss, (float*)d_out);
}